// Round 7
// baseline (231.719 us; speedup 1.0000x reference)
//
#include <hip/hip_runtime.h>
#include <hip/hip_bf16.h>

// B=8, N=2048, D=384, R=64, H=W=256.
// Inputs:  x (B,N,D) f32, segments (B,H,W) i32, prototypes (1,R,D) f32.
// Outputs (f32, concat): out (B,N,D) | segments (B,H,W) | loss (1) | C (B,N,R)
//
// Pipeline (8 dispatches):
//   memset(maskp only, 64KB) ; k_proto ; k_seg (LDS-bitmask build) ; k_csim
//   (S normalized + colsum partials + bf16 xT) ; k_lossfc (loss partials +
//   C + Kbf) ; k_qk (P=mask.*ChatChat^T -> ws; BARRIER-FREE wave-autonomous
//   kt-panels, wave-local LDS repack) ; k_pv (out = diag(1/(P*1)) P X —
//   m97-structure LDS-staged GEMM) ; k_segout.
//
// k_qk history: per-tile version (8192 blocks, cross-wave barrier) = 49.7us
// at 1.3TB/s write — serial chain per tiny block, nothing saturated. This
// version: waves own 16 rows x 4 kt tiles, private LDS slice (no s_barrier
// at all -> no vmcnt drains), A-frags reused 4x, 512B/row write locality.
#define NB 8
#define NN 2048
#define ND 384
#define NR 64
#define OUT_ELEMS (NB*NN*ND)        // 6291456
#define SEG_ELEMS (NB*256*256)      // 524288
#define NBLK_LOSS (NB*NN/4)         // 4096

typedef float  f32x4  __attribute__((ext_vector_type(4)));
typedef short  bf16x8 __attribute__((ext_vector_type(8)));

__device__ inline float wsum(float v){
  #pragma unroll
  for(int o=32;o;o>>=1) v += __shfl_xor(v,o,64);
  return v;
}
__device__ inline float wmax(float v){
  #pragma unroll
  for(int o=32;o;o>>=1) v = fmaxf(v,__shfl_xor(v,o,64));
  return v;
}
__device__ inline unsigned short f2bf(float f){
  unsigned u = __float_as_uint(f);
  return (unsigned short)((u + 0x8000u) >> 16);
}

// async global->LDS, 16 B per lane; LDS dest is wave-uniform base + lane*16
__device__ __forceinline__ void gl2lds16(const unsigned short* g, unsigned short* s){
  __builtin_amdgcn_global_load_lds(
      (const __attribute__((address_space(1))) unsigned int*)g,
      (__attribute__((address_space(3))) unsigned int*)s,
      16, 0, 0);
}

// ---- normalize prototypes -> kn (f32, unit rows) ----
__global__ void k_proto(const float* __restrict__ protos, float* __restrict__ kn){
  int r = blockIdx.x, l = threadIdx.x;
  float v[6]; float ss = 0.f;
  #pragma unroll
  for(int i=0;i<6;i++){ v[i] = protos[r*ND + l*6 + i]; ss += v[i]*v[i]; }
  ss = wsum(ss);
  float inv = 1.f / fmaxf(sqrtf(ss), 1e-8f);
  #pragma unroll
  for(int i=0;i<6;i++) kn[r*ND + l*6 + i] = v[i]*inv;
}

// ---- segments -> node mask + prox bitmask rows, built in LDS ----
// grid 256: b=bid&7 (batch), rg=bid>>3 (64-node range). 1024 threads.
__global__ __launch_bounds__(1024) void k_seg(const int* __restrict__ seg,
                                              float* __restrict__ mask,
                                              unsigned* __restrict__ prox){
  __shared__ unsigned lm[64*64];    // 16 KB
  int tid = threadIdx.x;
  int b  = blockIdx.x & 7;
  int rg = blockIdx.x >> 3;         // 0..31
  int base = rg << 6;
  for(int i=tid; i<64*64; i+=1024) lm[i] = 0u;
  __syncthreads();
  const int* sb = seg + b*65536;

#define PAIR(S, S2) { \
    if((S) != (S2) && (S) != 0 && (S2) != 0){ \
      if(((S )>>6)==rg) atomicOr(&lm[(((S )&63)<<6) + ((S2)>>5)], 1u<<((S2)&31)); \
      if(((S2)>>6)==rg) atomicOr(&lm[(((S2)&63)<<6) + ((S )>>5)], 1u<<((S )&31)); \
    } }

  #pragma unroll 1
  for(int it=0; it<16; ++it){
    int g = it*1024 + tid;          // int4 group index in [0,16384)
    int p = g*4;
    int i = g >> 6;                 // row 0..255
    int j = (g & 63)*4;             // col 0,4,...,252
    int4 a = *(const int4*)(sb + p);
    if((a.x>>6)==rg) mask[(b<<11) + a.x] = 1.f;
    if((a.y>>6)==rg) mask[(b<<11) + a.y] = 1.f;
    if((a.z>>6)==rg) mask[(b<<11) + a.z] = 1.f;
    if((a.w>>6)==rg) mask[(b<<11) + a.w] = 1.f;
    PAIR(a.x, a.y); PAIR(a.y, a.z); PAIR(a.z, a.w);
    if(j < 252){
      int n = sb[p + 4];
      PAIR(a.w, n);
    }
    if(i < 255){
      int4 v = *(const int4*)(sb + p + 256);
      PAIR(a.x, v.x); PAIR(a.y, v.y); PAIR(a.z, v.z); PAIR(a.w, v.w);
    }
  }
#undef PAIR
  __syncthreads();
  unsigned* dst = prox + ((size_t)(b<<11) + base)*64;
  *(uint4*)(dst + tid*4) = *(const uint4*)&lm[tid*4];
}

// ---- Csim GEMM: writes NORMALIZED s, colsum partials, bf16 xT ----
__global__ __launch_bounds__(256) void k_csim(const float* __restrict__ x,
                                              const float* __restrict__ kn,
                                              float* __restrict__ Sout,
                                              unsigned short* __restrict__ xTbf,
                                              float* __restrict__ part){
  __shared__ float xT[32*68];
  __shared__ float kT[32*68];
  __shared__ float xinvS[64];
  __shared__ float csh[16*64];
  int t = threadIdx.x;
  int m0 = blockIdx.x * 64;
  float acc[4][4] = {};
  int mload = t>>2, koff = (t&3)*8;
  int mb = (t>>4)*4, rb = (t&15)*4;
  float ssq = 0.f;
  for(int c=0;c<12;c++){
    int k0 = c*32;
    __syncthreads();
    const float4* xg = (const float4*)(x + (size_t)(m0+mload)*ND + k0 + koff);
    float4 a = xg[0], bq = xg[1];
    ssq += a.x*a.x + a.y*a.y + a.z*a.z + a.w*a.w
         + bq.x*bq.x + bq.y*bq.y + bq.z*bq.z + bq.w*bq.w;
    xT[(koff+0)*68+mload]=a.x;  xT[(koff+1)*68+mload]=a.y;  xT[(koff+2)*68+mload]=a.z;  xT[(koff+3)*68+mload]=a.w;
    xT[(koff+4)*68+mload]=bq.x; xT[(koff+5)*68+mload]=bq.y; xT[(koff+6)*68+mload]=bq.z; xT[(koff+7)*68+mload]=bq.w;
    const float4* kg = (const float4*)(kn + mload*ND + k0 + koff);
    float4 ka = kg[0], kb = kg[1];
    kT[(koff+0)*68+mload]=ka.x; kT[(koff+1)*68+mload]=ka.y; kT[(koff+2)*68+mload]=ka.z; kT[(koff+3)*68+mload]=ka.w;
    kT[(koff+4)*68+mload]=kb.x; kT[(koff+5)*68+mload]=kb.y; kT[(koff+6)*68+mload]=kb.z; kT[(koff+7)*68+mload]=kb.w;
    __syncthreads();
    {
      int k2 = t>>3, mo = (t&7)*8;
      const float* src = &xT[k2*68 + mo];
      float4 aa = *(const float4*)src;
      float4 bb = *(const float4*)(src+4);
      uint4 o;
      o.x = (unsigned)f2bf(aa.x) | ((unsigned)f2bf(aa.y)<<16);
      o.y = (unsigned)f2bf(aa.z) | ((unsigned)f2bf(aa.w)<<16);
      o.z = (unsigned)f2bf(bb.x) | ((unsigned)f2bf(bb.y)<<16);
      o.w = (unsigned)f2bf(bb.z) | ((unsigned)f2bf(bb.w)<<16);
      int bb2 = m0 >> 11, ml = m0 & 2047;
      *(uint4*)(xTbf + ((size_t)(bb2*ND + k0 + k2))*NN + ml + mo) = o;
    }
    for(int k=0;k<32;k++){
      float xv[4], kv[4];
      *(float4*)xv = *(const float4*)&xT[k*68+mb];
      *(float4*)kv = *(const float4*)&kT[k*68+rb];
      #pragma unroll
      for(int mi=0;mi<4;mi++)
        #pragma unroll
        for(int ri=0;ri<4;ri++) acc[mi][ri] += xv[mi]*kv[ri];
    }
  }
  ssq += __shfl_xor(ssq,1,64);
  ssq += __shfl_xor(ssq,2,64);
  if((t&3)==0) xinvS[mload] = 1.f / fmaxf(sqrtf(ssq), 1e-8f);
  __syncthreads();
  float sv[4][4];
  #pragma unroll
  for(int mi=0;mi<4;mi++){
    float xin = xinvS[mb+mi];
    float rsum = 0.f;
    #pragma unroll
    for(int ri=0;ri<4;ri++){
      float vv = (acc[mi][ri]*xin + 1.f)*0.5f;
      sv[mi][ri] = vv; rsum += vv;
    }
    rsum += __shfl_xor(rsum,1,64);
    rsum += __shfl_xor(rsum,2,64);
    rsum += __shfl_xor(rsum,4,64);
    rsum += __shfl_xor(rsum,8,64);
    float inv = 1.f/rsum;
    #pragma unroll
    for(int ri=0;ri<4;ri++) sv[mi][ri] *= inv;
    *(float4*)&Sout[(size_t)(m0+mb+mi)*NR + rb] = *(const float4*)sv[mi];
  }
  {
    float4 pc;
    pc.x = sv[0][0]+sv[1][0]+sv[2][0]+sv[3][0];
    pc.y = sv[0][1]+sv[1][1]+sv[2][1]+sv[3][1];
    pc.z = sv[0][2]+sv[1][2]+sv[2][2]+sv[3][2];
    pc.w = sv[0][3]+sv[1][3]+sv[2][3]+sv[3][3];
    *(float4*)&csh[(t>>4)*64 + rb] = pc;
  }
  __syncthreads();
  if(t < 64){
    float a = 0.f;
    #pragma unroll
    for(int g=0;g<16;g++) a += csh[g*64 + t];
    part[(size_t)blockIdx.x*64 + t] = a;        // part[b*32+chunk][r]
  }
}

// ---- DEC KL loss (partial stores) + C=softmax(s) in place + Kbf ----
__global__ void k_lossfc(float* Smat, const float* __restrict__ part,
                         const float* __restrict__ mask,
                         float* __restrict__ klp, float* __restrict__ mp,
                         unsigned short* __restrict__ Kbf){
  __shared__ float shk[4], shm[4];
  int w = threadIdx.x>>6, l = threadIdx.x&63;
  int node = blockIdx.x*4 + w;
  int b = node >> 11;
  float s = Smat[(size_t)node*NR + l];
  float csm = 0.f;
  #pragma unroll
  for(int c=0;c<32;c++) csm += part[(size_t)((b<<5)+c)*64 + l];
  float p = s*s/(csm + 1e-8f);
  float ps = wsum(p);
  float P = p/(ps + 1e-8f);
  float term = P*(logf(P + 1e-8f) - logf(s + 1e-8f));
  float kl = wsum(term);
  if(l==0){ float mv = mask[node]; shk[w] = kl*mv; shm[w] = mv; }
  float mx = wmax(s);
  float e = expf(s - mx);
  float Z = wsum(e);
  float c = e / Z;
  float cn2 = wsum(c*c);
  Smat[(size_t)node*NR + l] = c;
  Kbf[(size_t)node*NR + l] = f2bf(c * rsqrtf(cn2));
  __syncthreads();
  if(threadIdx.x==0){
    klp[blockIdx.x] = shk[0]+shk[1]+shk[2]+shk[3];
    mp [blockIdx.x] = shm[0]+shm[1]+shm[2]+shm[3];
  }
}

// ---- pass A: P = mask .* (Chat Chat^T), bf16 -> ws. BARRIER-FREE ----
// grid 2048: b=bid&7, qt=(bid>>3)&31, kc=bid>>8 (kt chunk of 4).
// Wave w owns rows qt*64 + w*16..+15 for ALL 4 kts of the chunk:
//   A-frags loaded once; per kt: 8 B-loads (L2) + 8 MFMA + prox mask +
//   wave-LOCAL LDS repack (private 16x72 slice; ds_write->ds_read within
//   the wave needs only lgkmcnt, no s_barrier) + 2 coalesced uint4 stores.
// Zero s_barrier => no vmcnt(0) drains; consecutive kts give 512B/row
// write locality.
__global__ __launch_bounds__(256) void k_qk(const unsigned short* __restrict__ Kbf,
                                            const unsigned* __restrict__ prox,
                                            unsigned short* __restrict__ Pbf){
  __shared__ short Plds[4][16*72];   // per-wave private slice, 9216 B total
  int tid = threadIdx.x;
  int w = tid>>6, l = tid&63, q = l>>4, li = l&15;
  int b  = blockIdx.x & 7;
  int qt = (blockIdx.x>>3) & 31;
  int kc = blockIdx.x >> 8;          // 0..7 (chunk of 4 kts)
  const unsigned short* Kb = Kbf + (size_t)b*NN*NR;
  short* myP = Plds[w];

  int arow = qt*64 + w*16 + li;
  bf16x8 af0 = *(const bf16x8*)(Kb + (size_t)arow*NR + q*8);
  bf16x8 af1 = *(const bf16x8*)(Kb + (size_t)arow*NR + 32 + q*8);

  int srow = l>>2, sg = l&3;         // store: row-in-wave 0..15, 16B seg 0..3

  #pragma unroll 1
  for(int kt = kc*4; kt < kc*4 + 4; ++kt){
    // prox masks early (latency hides under MFMA)
    uint2 mw[4];
    #pragma unroll
    for(int r=0;r<4;r++)
      mw[r] = *(const uint2*)(prox + ((size_t)(b*NN + qt*64 + w*16 + q*4 + r))*64 + kt*2);
    // B fragments: Chat rows kt*64 + f*16 + li
    bf16x8 b0[4], b1[4];
    #pragma unroll
    for(int f=0;f<4;f++){
      const unsigned short* p = Kb + (size_t)(kt*64 + f*16 + li)*NR + q*8;
      b0[f] = *(const bf16x8*)p;
      b1[f] = *(const bf16x8*)(p + 32);
    }
    f32x4 pacc[4] = {(f32x4)(0.f),(f32x4)(0.f),(f32x4)(0.f),(f32x4)(0.f)};
    #pragma unroll
    for(int f=0;f<4;f++){
      pacc[f] = __builtin_amdgcn_mfma_f32_16x16x32_bf16(af0, b0[f], pacc[f], 0,0,0);
      pacc[f] = __builtin_amdgcn_mfma_f32_16x16x32_bf16(af1, b1[f], pacc[f], 0,0,0);
    }
    // mask + write own LDS slice
    #pragma unroll
    for(int r=0;r<4;r++){
      int lrow = q*4 + r;                 // row-in-wave 0..15
      int brow = w*16 + lrow;             // row-in-block 0..63
      uint2 m = mw[r];
      if(qt==kt){                          // diagonal: global col == global row
        if((brow>>5)==0) m.x |= 1u<<(brow&31); else m.y |= 1u<<(brow&31);
      }
      #pragma unroll
      for(int f=0;f<4;f++){
        unsigned wd = (f<2) ? m.x : m.y;
        float v = ((wd >> ((f&1)*16 + li)) & 1u) ? pacc[f][r] : 0.f;
        myP[lrow*72 + f*16 + li] = (short)f2bf(v);
      }
    }
    // wave-local readback + coalesced store (compiler inserts lgkmcnt)
    const uint4* src = (const uint4*)&myP[srow*72 + sg*16];
    unsigned short* dst = Pbf + ((size_t)(b*NN + qt*64 + w*16 + srow))*NN + kt*64 + sg*16;
    uint4 v0 = src[0], v1 = *(const uint4*)((const short*)src + 8);
    *(uint4*)dst = v0;
    *(uint4*)(dst + 8) = v1;
  }
}

// ---- pass B: out = diag(1/(P*1)) P X — m97-structure LDS-staged GEMM ----
// BM=64, BN=128, BK=32. grid 768: b=bid&7, mt=(bid>>3)&31, ct=bid>>8.
__global__ __launch_bounds__(256, 3) void k_pv(const unsigned short* __restrict__ Pbf,
                                               const unsigned short* __restrict__ xTbf,
                                               float* __restrict__ out){
  __shared__ unsigned short Al[64*32];     // 4 KB
  __shared__ unsigned short Bl[128*32];    // 8 KB
  int tid = threadIdx.x;
  int w = tid>>6, l = tid&63, q = l>>4, li = l&15;
  int b  = blockIdx.x & 7;
  int mt = (blockIdx.x>>3) & 31;
  int ct = blockIdx.x >> 8;                // 0..2
  int m0 = mt*64;
  int d0 = ct*128;
  const unsigned short* Pb  = Pbf  + (size_t)b*NN*NN;
  const unsigned short* xTb = xTbf + (size_t)b*ND*NN;

  int wr = w & 1, wc = w >> 1;

  int lr = l>>2, lk = (l&3)*8;             // lane -> row-in-chunk, k-elems
  const unsigned short* gsrc0; const unsigned short* gsrc1; const unsigned short* gsrc2;
  unsigned short* ldst0; unsigned short* ldst1; unsigned short* ldst2;
  {
    int id0 = w*3, id1 = w*3+1, id2 = w*3+2;
    ldst0 = (id0<4 ? Al + id0*512 : Bl + (id0-4)*512);
    ldst1 = (id1<4 ? Al + id1*512 : Bl + (id1-4)*512);
    ldst2 = (id2<4 ? Al + id2*512 : Bl + (id2-4)*512);
    gsrc0 = (id0<4 ? Pb + (size_t)(m0 + id0*16 + lr)*NN + lk
                   : xTb + (size_t)(d0 + (id0-4)*16 + lr)*NN + lk);
    gsrc1 = (id1<4 ? Pb + (size_t)(m0 + id1*16 + lr)*NN + lk
                   : xTb + (size_t)(d0 + (id1-4)*16 + lr)*NN + lk);
    gsrc2 = (id2<4 ? Pb + (size_t)(m0 + id2*16 + lr)*NN + lk
                   : xTb + (size_t)(d0 + (id2-4)*16 + lr)*NN + lk);
  }

  f32x4 acc[2][4];
  #pragma unroll
  for(int nc=0;nc<2;nc++)
    #pragma unroll
    for(int t=0;t<4;t++) acc[nc][t] = (f32x4)(0.f);
  f32x4 rs[2] = {(f32x4)(0.f),(f32x4)(0.f)};
  bf16x8 ones;
  #pragma unroll
  for(int i=0;i<8;i++) ones[i] = (short)0x3F80;   // bf16 1.0

  for(int k0=0; k0<NN; k0+=32){
    __syncthreads();                       // previous compute done (LDS reuse)
    gl2lds16(gsrc0 + k0, ldst0);
    gl2lds16(gsrc1 + k0, ldst1);
    gl2lds16(gsrc2 + k0, ldst2);
    __syncthreads();                       // staging visible (vmcnt drain)
    bf16x8 a0 = *(const bf16x8*)&Al[(wr*32 +      li)*32 + q*8];
    bf16x8 a1 = *(const bf16x8*)&Al[(wr*32 + 16 + li)*32 + q*8];
    bf16x8 bv[4];
    #pragma unroll
    for(int t=0;t<4;t++)
      bv[t] = *(const bf16x8*)&Bl[(wc*64 + t*16 + li)*32 + q*8];
    #pragma unroll
    for(int t=0;t<4;t++){
      acc[0][t] = __builtin_amdgcn_mfma_f32_16x16x32_bf16(a0, bv[t], acc[0][t], 0,0,0);
      acc[1][t] = __builtin_amdgcn_mfma_f32_16x16x32_bf16(a1, bv[t], acc[1][t], 0,0,0);
    }
    rs[0] = __builtin_amdgcn_mfma_f32_16x16x32_bf16(a0, ones, rs[0], 0,0,0);
    rs[1] = __builtin_amdgcn_mfma_f32_16x16x32_bf16(a1, ones, rs[1], 0,0,0);
  }

  #pragma unroll
  for(int nc=0;nc<2;nc++)
    #pragma unroll
    for(int r=0;r<4;r++){
      int row = m0 + wr*32 + nc*16 + q*4 + r;
      float inv = 1.f/(rs[nc][r] + 1e-8f);
      float* orow = out + ((size_t)(b*NN + row))*ND + d0 + wc*64;
      #pragma unroll
      for(int t=0;t<4;t++)
        orow[t*16 + li] = acc[nc][t][r] * inv;
    }
}

// ---- segout; block 0 also reduces the loss partials ----
__global__ void k_segout(const int* __restrict__ seg, float* __restrict__ o,
                         const float* __restrict__ klp, const float* __restrict__ mp,
                         float* __restrict__ outLoss){
  int tid = threadIdx.x;
  int i = blockIdx.x*256 + tid;
  o[i] = (float)seg[i];
  if(blockIdx.x==0){
    __shared__ float sa[4], sm[4];
    float a=0.f, m=0.f;
    for(int k=tid; k<NBLK_LOSS; k+=256){ a += klp[k]; m += mp[k]; }
    a = wsum(a); m = wsum(m);
    if((tid&63)==0){ sa[tid>>6]=a; sm[tid>>6]=m; }
    __syncthreads();
    if(tid==0)
      outLoss[0] = (sa[0]+sa[1]+sa[2]+sa[3])/((sm[0]+sm[1]+sm[2]+sm[3])+1e-8f);
  }
}

extern "C" void kernel_launch(void* const* d_in, const int* in_sizes, int n_in,
                              void* d_out, int out_size, void* d_ws, size_t ws_size,
                              hipStream_t stream) {
  const float* x      = (const float*)d_in[0];
  const int*   seg    = (const int*)d_in[1];
  const float* protos = (const float*)d_in[2];

  float* out     = (float*)d_out;                  // (B,N,D)
  float* outSeg  = out + OUT_ELEMS;                // (B,H,W)
  float* outLoss = outSeg + SEG_ELEMS;             // scalar
  float* outC    = outLoss + 1;                    // (B,N,R)

  // ws layout (~83 MB)
  unsigned short* xTbf = (unsigned short*)d_ws;            // 8*384*2048 bf16 (12.6MB)
  unsigned short* Kbf  = xTbf + (size_t)NB*ND*NN;          // 8*2048*64 bf16 (2MB)
  unsigned short* Pbf  = Kbf + (size_t)NB*NN*NR;           // 8*2048*2048 bf16 (64MB)
  float* kn      = (float*)(Pbf + (size_t)NB*NN*NN);       // 24576 f32
  float* maskp   = kn + NR*ND;                             // 16384  -- zero region (64KB)
  unsigned* prox = (unsigned*)(maskp + NB*NN);             // 8*2048*64 u32 (4MB, fully written by k_seg)
  float* part    = (float*)(prox + (size_t)NB*NN*64);      // 8*32*64 (fully written)
  float* klp     = part + NB*32*64;                        // 4096 (fully written)
  float* mp      = klp + NBLK_LOSS;                        // 4096 (fully written)

  // only maskp needs zeroing (prox is fully written by k_seg)
  hipMemsetAsync(maskp, 0, (size_t)NB*NN*4, stream);

  k_proto <<<dim3(NR),           dim3(64),   0, stream>>>(protos, kn);
  k_seg   <<<dim3(256),          dim3(1024), 0, stream>>>(seg, maskp, prox);
  k_csim  <<<dim3(NB*NN/64),     dim3(256),  0, stream>>>(x, kn, outC, xTbf, part);
  k_lossfc<<<dim3(NBLK_LOSS),    dim3(256),  0, stream>>>(outC, part, maskp, klp, mp, Kbf);
  k_qk    <<<dim3(2048),         dim3(256),  0, stream>>>(Kbf, prox, Pbf);
  k_pv    <<<dim3(768),          dim3(256),  0, stream>>>(Pbf, xTbf, out);
  k_segout<<<dim3(SEG_ELEMS/256),dim3(256),  0, stream>>>(seg, outSeg, klp, mp, outLoss);
}

// Round 8
// 216.538 us; speedup vs baseline: 1.0701x; 1.0701x over previous
//
#include <hip/hip_runtime.h>
#include <hip/hip_bf16.h>

// B=8, N=2048, D=384, R=64, H=W=256.
// Inputs:  x (B,N,D) f32, segments (B,H,W) i32, prototypes (1,R,D) f32.
// Outputs (f32, concat): out (B,N,D) | segments (B,H,W) | loss (1) | C (B,N,R)
//
// Pipeline (8 dispatches):
//   memset(maskp only, 64KB) ; k_proto ; k_seg (LDS-bitmask build) ; k_csim
//   (S normalized + colsum partials + bf16 xT) ; k_lossfc (loss partials +
//   C + Kbf) ; k_qk (P=mask.*ChatChat^T -> ws; barrier-free wave-autonomous
//   kt-panels) ; k_pv (out = diag(1/(P*1)) P X — LDS-staged GEMM, BK=64,
//   both-sides XOR swizzle) ; k_segout.
//
// k_pv history: reg-direct (3 variants) 108us pinned; m97 LDS-staged BK=32 =
// 49.5us but SQ_LDS_BANK_CONFLICT 4.7M (64B rows -> 8-way conflict on
// ds_read_b128, fixed q puts 8 even rows on same 4 banks) + 64 barrier
// drains. This version: BK=64 (32 steps, 20 MFMA/wave/step) + rule-#21
// both-sides swizzle (linear LDS dest, pre-swizzled global src seg_g =
// (l&7)^(l>>3), ds_read phys seg = logical^(row&7)) -> 2-way (free).
#define NB 8
#define NN 2048
#define ND 384
#define NR 64
#define OUT_ELEMS (NB*NN*ND)        // 6291456
#define SEG_ELEMS (NB*256*256)      // 524288
#define NBLK_LOSS (NB*NN/4)         // 4096

typedef float  f32x4  __attribute__((ext_vector_type(4)));
typedef short  bf16x8 __attribute__((ext_vector_type(8)));

__device__ inline float wsum(float v){
  #pragma unroll
  for(int o=32;o;o>>=1) v += __shfl_xor(v,o,64);
  return v;
}
__device__ inline float wmax(float v){
  #pragma unroll
  for(int o=32;o;o>>=1) v = fmaxf(v,__shfl_xor(v,o,64));
  return v;
}
__device__ inline unsigned short f2bf(float f){
  unsigned u = __float_as_uint(f);
  return (unsigned short)((u + 0x8000u) >> 16);
}

// async global->LDS, 16 B per lane; LDS dest is wave-uniform base + lane*16
__device__ __forceinline__ void gl2lds16(const unsigned short* g, unsigned short* s){
  __builtin_amdgcn_global_load_lds(
      (const __attribute__((address_space(1))) unsigned int*)g,
      (__attribute__((address_space(3))) unsigned int*)s,
      16, 0, 0);
}

// ---- normalize prototypes -> kn (f32, unit rows) ----
__global__ void k_proto(const float* __restrict__ protos, float* __restrict__ kn){
  int r = blockIdx.x, l = threadIdx.x;
  float v[6]; float ss = 0.f;
  #pragma unroll
  for(int i=0;i<6;i++){ v[i] = protos[r*ND + l*6 + i]; ss += v[i]*v[i]; }
  ss = wsum(ss);
  float inv = 1.f / fmaxf(sqrtf(ss), 1e-8f);
  #pragma unroll
  for(int i=0;i<6;i++) kn[r*ND + l*6 + i] = v[i]*inv;
}

// ---- segments -> node mask + prox bitmask rows, built in LDS ----
// grid 256: b=bid&7 (batch), rg=bid>>3 (64-node range). 1024 threads.
__global__ __launch_bounds__(1024) void k_seg(const int* __restrict__ seg,
                                              float* __restrict__ mask,
                                              unsigned* __restrict__ prox){
  __shared__ unsigned lm[64*64];    // 16 KB
  int tid = threadIdx.x;
  int b  = blockIdx.x & 7;
  int rg = blockIdx.x >> 3;         // 0..31
  int base = rg << 6;
  for(int i=tid; i<64*64; i+=1024) lm[i] = 0u;
  __syncthreads();
  const int* sb = seg + b*65536;

#define PAIR(S, S2) { \
    if((S) != (S2) && (S) != 0 && (S2) != 0){ \
      if(((S )>>6)==rg) atomicOr(&lm[(((S )&63)<<6) + ((S2)>>5)], 1u<<((S2)&31)); \
      if(((S2)>>6)==rg) atomicOr(&lm[(((S2)&63)<<6) + ((S )>>5)], 1u<<((S )&31)); \
    } }

  #pragma unroll 1
  for(int it=0; it<16; ++it){
    int g = it*1024 + tid;          // int4 group index in [0,16384)
    int p = g*4;
    int i = g >> 6;                 // row 0..255
    int j = (g & 63)*4;             // col 0,4,...,252
    int4 a = *(const int4*)(sb + p);
    if((a.x>>6)==rg) mask[(b<<11) + a.x] = 1.f;
    if((a.y>>6)==rg) mask[(b<<11) + a.y] = 1.f;
    if((a.z>>6)==rg) mask[(b<<11) + a.z] = 1.f;
    if((a.w>>6)==rg) mask[(b<<11) + a.w] = 1.f;
    PAIR(a.x, a.y); PAIR(a.y, a.z); PAIR(a.z, a.w);
    if(j < 252){
      int n = sb[p + 4];
      PAIR(a.w, n);
    }
    if(i < 255){
      int4 v = *(const int4*)(sb + p + 256);
      PAIR(a.x, v.x); PAIR(a.y, v.y); PAIR(a.z, v.z); PAIR(a.w, v.w);
    }
  }
#undef PAIR
  __syncthreads();
  unsigned* dst = prox + ((size_t)(b<<11) + base)*64;
  *(uint4*)(dst + tid*4) = *(const uint4*)&lm[tid*4];
}

// ---- Csim GEMM: writes NORMALIZED s, colsum partials, bf16 xT ----
__global__ __launch_bounds__(256) void k_csim(const float* __restrict__ x,
                                              const float* __restrict__ kn,
                                              float* __restrict__ Sout,
                                              unsigned short* __restrict__ xTbf,
                                              float* __restrict__ part){
  __shared__ float xT[32*68];
  __shared__ float kT[32*68];
  __shared__ float xinvS[64];
  __shared__ float csh[16*64];
  int t = threadIdx.x;
  int m0 = blockIdx.x * 64;
  float acc[4][4] = {};
  int mload = t>>2, koff = (t&3)*8;
  int mb = (t>>4)*4, rb = (t&15)*4;
  float ssq = 0.f;
  for(int c=0;c<12;c++){
    int k0 = c*32;
    __syncthreads();
    const float4* xg = (const float4*)(x + (size_t)(m0+mload)*ND + k0 + koff);
    float4 a = xg[0], bq = xg[1];
    ssq += a.x*a.x + a.y*a.y + a.z*a.z + a.w*a.w
         + bq.x*bq.x + bq.y*bq.y + bq.z*bq.z + bq.w*bq.w;
    xT[(koff+0)*68+mload]=a.x;  xT[(koff+1)*68+mload]=a.y;  xT[(koff+2)*68+mload]=a.z;  xT[(koff+3)*68+mload]=a.w;
    xT[(koff+4)*68+mload]=bq.x; xT[(koff+5)*68+mload]=bq.y; xT[(koff+6)*68+mload]=bq.z; xT[(koff+7)*68+mload]=bq.w;
    const float4* kg = (const float4*)(kn + mload*ND + k0 + koff);
    float4 ka = kg[0], kb = kg[1];
    kT[(koff+0)*68+mload]=ka.x; kT[(koff+1)*68+mload]=ka.y; kT[(koff+2)*68+mload]=ka.z; kT[(koff+3)*68+mload]=ka.w;
    kT[(koff+4)*68+mload]=kb.x; kT[(koff+5)*68+mload]=kb.y; kT[(koff+6)*68+mload]=kb.z; kT[(koff+7)*68+mload]=kb.w;
    __syncthreads();
    {
      int k2 = t>>3, mo = (t&7)*8;
      const float* src = &xT[k2*68 + mo];
      float4 aa = *(const float4*)src;
      float4 bb = *(const float4*)(src+4);
      uint4 o;
      o.x = (unsigned)f2bf(aa.x) | ((unsigned)f2bf(aa.y)<<16);
      o.y = (unsigned)f2bf(aa.z) | ((unsigned)f2bf(aa.w)<<16);
      o.z = (unsigned)f2bf(bb.x) | ((unsigned)f2bf(bb.y)<<16);
      o.w = (unsigned)f2bf(bb.z) | ((unsigned)f2bf(bb.w)<<16);
      int bb2 = m0 >> 11, ml = m0 & 2047;
      *(uint4*)(xTbf + ((size_t)(bb2*ND + k0 + k2))*NN + ml + mo) = o;
    }
    for(int k=0;k<32;k++){
      float xv[4], kv[4];
      *(float4*)xv = *(const float4*)&xT[k*68+mb];
      *(float4*)kv = *(const float4*)&kT[k*68+rb];
      #pragma unroll
      for(int mi=0;mi<4;mi++)
        #pragma unroll
        for(int ri=0;ri<4;ri++) acc[mi][ri] += xv[mi]*kv[ri];
    }
  }
  ssq += __shfl_xor(ssq,1,64);
  ssq += __shfl_xor(ssq,2,64);
  if((t&3)==0) xinvS[mload] = 1.f / fmaxf(sqrtf(ssq), 1e-8f);
  __syncthreads();
  float sv[4][4];
  #pragma unroll
  for(int mi=0;mi<4;mi++){
    float xin = xinvS[mb+mi];
    float rsum = 0.f;
    #pragma unroll
    for(int ri=0;ri<4;ri++){
      float vv = (acc[mi][ri]*xin + 1.f)*0.5f;
      sv[mi][ri] = vv; rsum += vv;
    }
    rsum += __shfl_xor(rsum,1,64);
    rsum += __shfl_xor(rsum,2,64);
    rsum += __shfl_xor(rsum,4,64);
    rsum += __shfl_xor(rsum,8,64);
    float inv = 1.f/rsum;
    #pragma unroll
    for(int ri=0;ri<4;ri++) sv[mi][ri] *= inv;
    *(float4*)&Sout[(size_t)(m0+mb+mi)*NR + rb] = *(const float4*)sv[mi];
  }
  {
    float4 pc;
    pc.x = sv[0][0]+sv[1][0]+sv[2][0]+sv[3][0];
    pc.y = sv[0][1]+sv[1][1]+sv[2][1]+sv[3][1];
    pc.z = sv[0][2]+sv[1][2]+sv[2][2]+sv[3][2];
    pc.w = sv[0][3]+sv[1][3]+sv[2][3]+sv[3][3];
    *(float4*)&csh[(t>>4)*64 + rb] = pc;
  }
  __syncthreads();
  if(t < 64){
    float a = 0.f;
    #pragma unroll
    for(int g=0;g<16;g++) a += csh[g*64 + t];
    part[(size_t)blockIdx.x*64 + t] = a;        // part[b*32+chunk][r]
  }
}

// ---- DEC KL loss (partial stores) + C=softmax(s) in place + Kbf ----
__global__ void k_lossfc(float* Smat, const float* __restrict__ part,
                         const float* __restrict__ mask,
                         float* __restrict__ klp, float* __restrict__ mp,
                         unsigned short* __restrict__ Kbf){
  __shared__ float shk[4], shm[4];
  int w = threadIdx.x>>6, l = threadIdx.x&63;
  int node = blockIdx.x*4 + w;
  int b = node >> 11;
  float s = Smat[(size_t)node*NR + l];
  float csm = 0.f;
  #pragma unroll
  for(int c=0;c<32;c++) csm += part[(size_t)((b<<5)+c)*64 + l];
  float p = s*s/(csm + 1e-8f);
  float ps = wsum(p);
  float P = p/(ps + 1e-8f);
  float term = P*(logf(P + 1e-8f) - logf(s + 1e-8f));
  float kl = wsum(term);
  if(l==0){ float mv = mask[node]; shk[w] = kl*mv; shm[w] = mv; }
  float mx = wmax(s);
  float e = expf(s - mx);
  float Z = wsum(e);
  float c = e / Z;
  float cn2 = wsum(c*c);
  Smat[(size_t)node*NR + l] = c;
  Kbf[(size_t)node*NR + l] = f2bf(c * rsqrtf(cn2));
  __syncthreads();
  if(threadIdx.x==0){
    klp[blockIdx.x] = shk[0]+shk[1]+shk[2]+shk[3];
    mp [blockIdx.x] = shm[0]+shm[1]+shm[2]+shm[3];
  }
}

// ---- pass A: P = mask .* (Chat Chat^T), bf16 -> ws. BARRIER-FREE ----
// grid 2048: b=bid&7, qt=(bid>>3)&31, kc=bid>>8 (kt chunk of 4).
__global__ __launch_bounds__(256) void k_qk(const unsigned short* __restrict__ Kbf,
                                            const unsigned* __restrict__ prox,
                                            unsigned short* __restrict__ Pbf){
  __shared__ short Plds[4][16*72];   // per-wave private slice, 9216 B total
  int tid = threadIdx.x;
  int w = tid>>6, l = tid&63, q = l>>4, li = l&15;
  int b  = blockIdx.x & 7;
  int qt = (blockIdx.x>>3) & 31;
  int kc = blockIdx.x >> 8;          // 0..7 (chunk of 4 kts)
  const unsigned short* Kb = Kbf + (size_t)b*NN*NR;
  short* myP = Plds[w];

  int arow = qt*64 + w*16 + li;
  bf16x8 af0 = *(const bf16x8*)(Kb + (size_t)arow*NR + q*8);
  bf16x8 af1 = *(const bf16x8*)(Kb + (size_t)arow*NR + 32 + q*8);

  int srow = l>>2, sg = l&3;         // store: row-in-wave 0..15, 16B seg 0..3

  #pragma unroll 1
  for(int kt = kc*4; kt < kc*4 + 4; ++kt){
    uint2 mw[4];
    #pragma unroll
    for(int r=0;r<4;r++)
      mw[r] = *(const uint2*)(prox + ((size_t)(b*NN + qt*64 + w*16 + q*4 + r))*64 + kt*2);
    bf16x8 b0[4], b1[4];
    #pragma unroll
    for(int f=0;f<4;f++){
      const unsigned short* p = Kb + (size_t)(kt*64 + f*16 + li)*NR + q*8;
      b0[f] = *(const bf16x8*)p;
      b1[f] = *(const bf16x8*)(p + 32);
    }
    f32x4 pacc[4] = {(f32x4)(0.f),(f32x4)(0.f),(f32x4)(0.f),(f32x4)(0.f)};
    #pragma unroll
    for(int f=0;f<4;f++){
      pacc[f] = __builtin_amdgcn_mfma_f32_16x16x32_bf16(af0, b0[f], pacc[f], 0,0,0);
      pacc[f] = __builtin_amdgcn_mfma_f32_16x16x32_bf16(af1, b1[f], pacc[f], 0,0,0);
    }
    #pragma unroll
    for(int r=0;r<4;r++){
      int lrow = q*4 + r;                 // row-in-wave 0..15
      int brow = w*16 + lrow;             // row-in-block 0..63
      uint2 m = mw[r];
      if(qt==kt){
        if((brow>>5)==0) m.x |= 1u<<(brow&31); else m.y |= 1u<<(brow&31);
      }
      #pragma unroll
      for(int f=0;f<4;f++){
        unsigned wd = (f<2) ? m.x : m.y;
        float v = ((wd >> ((f&1)*16 + li)) & 1u) ? pacc[f][r] : 0.f;
        myP[lrow*72 + f*16 + li] = (short)f2bf(v);
      }
    }
    const uint4* src = (const uint4*)&myP[srow*72 + sg*16];
    unsigned short* dst = Pbf + ((size_t)(b*NN + qt*64 + w*16 + srow))*NN + kt*64 + sg*16;
    uint4 v0 = src[0], v1 = *(const uint4*)((const short*)src + 8);
    *(uint4*)dst = v0;
    *(uint4*)(dst + 8) = v1;
  }
}

// ---- pass B: out = diag(1/(P*1)) P X — LDS-staged GEMM, BK=64, swizzled ----
// BM=64, BN=128, BK=64. grid 768: b=bid&7, mt=(bid>>3)&31, ct=bid>>8.
// 4 waves: wave (wr=w&1, wc=w>>1) owns 32 rows x 64 cols. Per K-step:
// 24 gl2lds(1KB chunks: A 8 + B 16, 6/wave) ; barrier ; 2 k-subs x
// (6 ds_read_b128 + 10 MFMA). LDS 24KB -> 3 blocks/CU.
// Swizzle (rule #21): LDS dest linear; global src seg pre-swizzled
// seg_g=(l&7)^(l>>3); ds_read phys seg = (s*4+q)^(row&7) -> 2-way banks.
__global__ __launch_bounds__(256, 3) void k_pv(const unsigned short* __restrict__ Pbf,
                                               const unsigned short* __restrict__ xTbf,
                                               float* __restrict__ out){
  __shared__ unsigned short Al[64*64];     // 8 KB  (64 rows x 128B)
  __shared__ unsigned short Bl[128*64];    // 16 KB (128 rows x 128B)
  int tid = threadIdx.x;
  int w = tid>>6, l = tid&63, q = l>>4, li = l&15;
  int b  = blockIdx.x & 7;
  int mt = (blockIdx.x>>3) & 31;
  int ct = blockIdx.x >> 8;                // 0..2
  int m0 = mt*64;
  int d0 = ct*128;
  const unsigned short* Pb  = Pbf  + (size_t)b*NN*NN;
  const unsigned short* xTb = xTbf + (size_t)b*ND*NN;

  int wr = w & 1, wc = w >> 1;

  // staging: 24 chunks of 1KB (A: 0-7, B: 8-23); wave w issues chunks
  // w*6..w*6+5. Chunk = 8 rows x 128B; lane l -> row c*8+(l>>3), LDS linear
  // l*16; global source seg PRE-SWIZZLED: seg_g = (l&7) ^ (l>>3).
  int lrow8 = l>>3;
  int sgel  = ((l&7) ^ lrow8) * 8;         // swizzled 16B-seg, in elements
  const unsigned short* gsrc[6];
  unsigned short* ldst[6];
  #pragma unroll
  for(int j=0;j<6;j++){
    int id = w*6 + j;
    if(id < 8){
      ldst[j] = Al + id*512;
      gsrc[j] = Pb + (size_t)(m0 + id*8 + lrow8)*NN + sgel;
    }else{
      ldst[j] = Bl + (id-8)*512;
      gsrc[j] = xTb + (size_t)(d0 + (id-8)*8 + lrow8)*NN + sgel;
    }
  }

  f32x4 acc[2][4];
  #pragma unroll
  for(int nc=0;nc<2;nc++)
    #pragma unroll
    for(int t=0;t<4;t++) acc[nc][t] = (f32x4)(0.f);
  f32x4 rs[2] = {(f32x4)(0.f),(f32x4)(0.f)};
  bf16x8 ones;
  #pragma unroll
  for(int i=0;i<8;i++) ones[i] = (short)0x3F80;   // bf16 1.0

  int r7 = li & 7;                         // row&7 for all this wave's frag rows
  for(int k0=0; k0<NN; k0+=64){
    __syncthreads();                       // previous compute done (LDS reuse)
    #pragma unroll
    for(int j=0;j<6;j++) gl2lds16(gsrc[j] + k0, ldst[j]);
    __syncthreads();                       // staging visible (vmcnt drain)
    #pragma unroll
    for(int s=0;s<2;s++){
      int ps = ((s*4 + q) ^ r7) * 8;       // swizzled read seg (elements)
      bf16x8 a0 = *(const bf16x8*)&Al[(wr*32 +      li)*64 + ps];
      bf16x8 a1 = *(const bf16x8*)&Al[(wr*32 + 16 + li)*64 + ps];
      bf16x8 bv[4];
      #pragma unroll
      for(int t=0;t<4;t++)
        bv[t] = *(const bf16x8*)&Bl[(wc*64 + t*16 + li)*64 + ps];
      #pragma unroll
      for(int t=0;t<4;t++){
        acc[0][t] = __builtin_amdgcn_mfma_f32_16x16x32_bf16(a0, bv[t], acc[0][t], 0,0,0);
        acc[1][t] = __builtin_amdgcn_mfma_f32_16x16x32_bf16(a1, bv[t], acc[1][t], 0,0,0);
      }
      rs[0] = __builtin_amdgcn_mfma_f32_16x16x32_bf16(a0, ones, rs[0], 0,0,0);
      rs[1] = __builtin_amdgcn_mfma_f32_16x16x32_bf16(a1, ones, rs[1], 0,0,0);
    }
  }

  #pragma unroll
  for(int nc=0;nc<2;nc++)
    #pragma unroll
    for(int r=0;r<4;r++){
      int row = m0 + wr*32 + nc*16 + q*4 + r;
      float inv = 1.f/(rs[nc][r] + 1e-8f);
      float* orow = out + ((size_t)(b*NN + row))*ND + d0 + wc*64;
      #pragma unroll
      for(int t=0;t<4;t++)
        orow[t*16 + li] = acc[nc][t][r] * inv;
    }
}

// ---- segout; block 0 also reduces the loss partials ----
__global__ void k_segout(const int* __restrict__ seg, float* __restrict__ o,
                         const float* __restrict__ klp, const float* __restrict__ mp,
                         float* __restrict__ outLoss){
  int tid = threadIdx.x;
  int i = blockIdx.x*256 + tid;
  o[i] = (float)seg[i];
  if(blockIdx.x==0){
    __shared__ float sa[4], sm[4];
    float a=0.f, m=0.f;
    for(int k=tid; k<NBLK_LOSS; k+=256){ a += klp[k]; m += mp[k]; }
    a = wsum(a); m = wsum(m);
    if((tid&63)==0){ sa[tid>>6]=a; sm[tid>>6]=m; }
    __syncthreads();
    if(tid==0)
      outLoss[0] = (sa[0]+sa[1]+sa[2]+sa[3])/((sm[0]+sm[1]+sm[2]+sm[3])+1e-8f);
  }
}

extern "C" void kernel_launch(void* const* d_in, const int* in_sizes, int n_in,
                              void* d_out, int out_size, void* d_ws, size_t ws_size,
                              hipStream_t stream) {
  const float* x      = (const float*)d_in[0];
  const int*   seg    = (const int*)d_in[1];
  const float* protos = (const float*)d_in[2];

  float* out     = (float*)d_out;                  // (B,N,D)
  float* outSeg  = out + OUT_ELEMS;                // (B,H,W)
  float* outLoss = outSeg + SEG_ELEMS;             // scalar
  float* outC    = outLoss + 1;                    // (B,N,R)

  // ws layout (~83 MB)
  unsigned short* xTbf = (unsigned short*)d_ws;            // 8*384*2048 bf16 (12.6MB)
  unsigned short* Kbf  = xTbf + (size_t)NB*ND*NN;          // 8*2048*64 bf16 (2MB)
  unsigned short* Pbf  = Kbf + (size_t)NB*NN*NR;           // 8*2048*2048 bf16 (64MB)
  float* kn      = (float*)(Pbf + (size_t)NB*NN*NN);       // 24576 f32
  float* maskp   = kn + NR*ND;                             // 16384  -- zero region (64KB)
  unsigned* prox = (unsigned*)(maskp + NB*NN);             // 8*2048*64 u32 (4MB, fully written by k_seg)
  float* part    = (float*)(prox + (size_t)NB*NN*64);      // 8*32*64 (fully written)
  float* klp     = part + NB*32*64;                        // 4096 (fully written)
  float* mp      = klp + NBLK_LOSS;                        // 4096 (fully written)

  // only maskp needs zeroing (prox is fully written by k_seg)
  hipMemsetAsync(maskp, 0, (size_t)NB*NN*4, stream);

  k_proto <<<dim3(NR),           dim3(64),   0, stream>>>(protos, kn);
  k_seg   <<<dim3(256),          dim3(1024), 0, stream>>>(seg, maskp, prox);
  k_csim  <<<dim3(NB*NN/64),     dim3(256),  0, stream>>>(x, kn, outC, xTbf, part);
  k_lossfc<<<dim3(NBLK_LOSS),    dim3(256),  0, stream>>>(outC, part, maskp, klp, mp, Kbf);
  k_qk    <<<dim3(2048),         dim3(256),  0, stream>>>(Kbf, prox, Pbf);
  k_pv    <<<dim3(768),          dim3(256),  0, stream>>>(Pbf, xTbf, out);
  k_segout<<<dim3(SEG_ELEMS/256),dim3(256),  0, stream>>>(seg, outSeg, klp, mp, outLoss);
}